// Round 1
// baseline (286.119 us; speedup 1.0000x reference)
//
#include <hip/hip_runtime.h>
#include <hip/hip_fp16.h>

#define USER_NUM 100000
#define ITEM_NUM 150000
#define N_NODES  250000
#define EMB      64
#define N_EDGES  1200000
#define N_ELEM   (N_NODES * EMB)   // 16,000,000

#define NBLK1 512                  // phase-1 blocks
#define NBUCK 245                  // ceil(N_NODES/1024) buckets of 1024 rows
#define CAP   8192                 // records per bucket region in tmp
#define TB1   4096                 // phase-1 tile buffer (max padded 2344+245*7=4059)
#define INIT_BLOCKS 3907           // ceil(N_ELEM/16 / 256)

typedef int   i2 __attribute__((ext_vector_type(2)));
typedef int   i4 __attribute__((ext_vector_type(4)));
typedef float f4 __attribute__((ext_vector_type(4)));

// ---------------- phase 1: bin edges into 1024-row buckets ----------------
__global__ __launch_bounds__(256) void bin_kernel(
    const int* __restrict__ rows, const int* __restrict__ cols,
    const float* __restrict__ vals,
    int* __restrict__ chunkcur, int* __restrict__ bucket_cnt,
    int2* __restrict__ tmp)
{
    __shared__ int  scnt[256];     // per-bucket count, later placement cursor
    __shared__ int  spref[256];    // padded exclusive prefix (246 used)
    __shared__ int  schunk[NBUCK]; // global chunk base per bucket
    __shared__ int2 tilebuf[TB1];

    int b = blockIdx.x, t = threadIdx.x;
    int e0 = (int)((long long)b * N_EDGES / NBLK1);
    int e1 = (int)((long long)(b + 1) * N_EDGES / NBLK1);

    scnt[t] = 0;
    __syncthreads();
    for (int e = e0 + t; e < e1; e += 256)
        atomicAdd(&scnt[rows[e] >> 10], 1);
    __syncthreads();
    int realc = (t < NBUCK) ? scnt[t] : 0;
    int v     = (realc + 7) & ~7;            // pad to 8-record chunks
    __syncthreads();
    spref[t] = v;
    __syncthreads();
    for (int off = 1; off < 256; off <<= 1) {
        int u = (t >= off) ? spref[t - off] : 0;
        __syncthreads();
        spref[t] += u;
        __syncthreads();
    }
    int excl = spref[t] - v;
    __syncthreads();
    spref[t] = excl;                          // exclusive; spref[245]=total
    __syncthreads();
    int padded_total = spref[NBUCK];
    if (t < NBUCK) {
        schunk[t] = (v > 0) ? atomicAdd(&chunkcur[t], v >> 3) : 0;
        if (realc > 0) atomicAdd(&bucket_cnt[t], realc);
    }
    __syncthreads();
    scnt[t] = spref[t];
    for (int j = t; j < padded_total; j += 256)
        tilebuf[j] = make_int2(-1, 0);
    __syncthreads();
    for (int e = e0 + t; e < e1; e += 256) {
        int r  = rows[e];
        int lp = atomicAdd(&scnt[r >> 10], 1);
        tilebuf[lp] = make_int2(((r & 1023) << 18) | cols[e], __float_as_int(vals[e]));
    }
    __syncthreads();
    // flush: every bucket group a whole number of 64B-aligned chunks
    for (int j = t; j < padded_total; j += 256) {
        int lo = 0, hi = NBUCK;
        while (hi - lo > 1) {
            int mid = (lo + hi) >> 1;
            if (spref[mid] <= j) lo = mid; else hi = mid;
        }
        tmp[(size_t)lo * CAP + schunk[lo] * 8 + (j - spref[lo])] = tilebuf[j];
    }
}

// ---------------- scan of 245 bucket counts ----------------
__global__ void scan245_kernel(const int* __restrict__ bucket_cnt,
                               int* __restrict__ bucket_base,
                               int* __restrict__ row_ptr)
{
    __shared__ int s[256];
    int t = threadIdx.x;
    int v = (t < NBUCK) ? bucket_cnt[t] : 0;
    s[t] = v;
    __syncthreads();
    for (int off = 1; off < 256; off <<= 1) {
        int u = (t >= off) ? s[t - off] : 0;
        __syncthreads();
        s[t] += u;
        __syncthreads();
    }
    if (t <= NBUCK) bucket_base[t] = s[t] - v;
    if (t == 0) row_ptr[N_NODES] = N_EDGES;
}

// ------- phase 2 (fused): blocks [0,NBUCK) place CSR; rest do fp16 init -------
__global__ __launch_bounds__(256) void place_init_kernel(
    const int* __restrict__ chunkcur, const int* __restrict__ bucket_base,
    const int2* __restrict__ tmp,
    int* __restrict__ row_ptr, int2* __restrict__ edges,
    const float* __restrict__ user, const float* __restrict__ item,
    __half* __restrict__ emb16)
{
    __shared__ int  shist[1024];
    __shared__ int  swave[256];
    __shared__ int2 sstage[CAP];   // 64KB

    int t = threadIdx.x;
    if (blockIdx.x >= NBUCK) {
        // ---- init path: 16 elems/thread, fp32 user||item -> fp16 table ----
        int gi = (blockIdx.x - NBUCK) * 256 + t;
        if (gi < N_ELEM / 16) {
            int base = gi * 16;
            const int UE = USER_NUM * EMB;   // 6.4M, 16-aligned
            const f4* src = (base < UE) ? (const f4*)(user + base)
                                        : (const f4*)(item + (base - UE));
            f4 f0 = __builtin_nontemporal_load(src);
            f4 f1 = __builtin_nontemporal_load(src + 1);
            f4 f2 = __builtin_nontemporal_load(src + 2);
            f4 f3 = __builtin_nontemporal_load(src + 3);
            union { i4 v; __half2 h[4]; } a, b;
            a.h[0] = __float22half2_rn(make_float2(f0.x, f0.y));
            a.h[1] = __float22half2_rn(make_float2(f0.z, f0.w));
            a.h[2] = __float22half2_rn(make_float2(f1.x, f1.y));
            a.h[3] = __float22half2_rn(make_float2(f1.z, f1.w));
            b.h[0] = __float22half2_rn(make_float2(f2.x, f2.y));
            b.h[1] = __float22half2_rn(make_float2(f2.z, f2.w));
            b.h[2] = __float22half2_rn(make_float2(f3.x, f3.y));
            b.h[3] = __float22half2_rn(make_float2(f3.z, f3.w));
            ((i4*)(emb16 + base))[0] = a.v;
            ((i4*)(emb16 + base))[1] = b.v;
        }
        return;
    }

    // ---- place path ----
    int b = blockIdx.x;
    int nrec = chunkcur[b] * 8;
    const int2* src = tmp + (size_t)b * CAP;

    for (int i = t; i < 1024; i += 256) shist[i] = 0;
    __syncthreads();
    for (int j = t; j < nrec; j += 256) {
        int x = src[j].x;
        if (x != -1) atomicAdd(&shist[x >> 18], 1);
    }
    __syncthreads();
    int h0 = shist[4 * t], h1 = shist[4 * t + 1], h2 = shist[4 * t + 2], h3 = shist[4 * t + 3];
    int sum = h0 + h1 + h2 + h3;
    swave[t] = sum;
    __syncthreads();
    for (int off = 1; off < 256; off <<= 1) {
        int u = (t >= off) ? swave[t - off] : 0;
        __syncthreads();
        swave[t] += u;
        __syncthreads();
    }
    int base = swave[t] - sum;
    __syncthreads();
    shist[4 * t]     = base;
    shist[4 * t + 1] = base + h0;
    shist[4 * t + 2] = base + h0 + h1;
    shist[4 * t + 3] = base + h0 + h1 + h2;
    __syncthreads();
    int bb = bucket_base[b];
    for (int i = t; i < 1024; i += 256) {
        int idx = b * 1024 + i;
        if (idx < N_NODES) row_ptr[idx] = bb + shist[i];
    }
    __syncthreads();
    for (int j = t; j < nrec; j += 256) {
        int2 rec = src[j];
        if (rec.x != -1) {
            int lp = atomicAdd(&shist[rec.x >> 18], 1);
            sstage[lp] = make_int2(rec.x & 0x3FFFF, rec.y);
        }
    }
    __syncthreads();
    int cnt = bucket_base[b + 1] - bb;
    for (int j = t; j < cnt; j += 256)
        edges[bb + j] = sstage[j];
}

// ---------------- fused SpMM: eighth-wave (8 lanes) per row, ILP-8, int4 gathers ----------------
// Lane l owns dims [8l, 8l+8). MODE 0: cur_out = acc (fp16, nt store).
// MODE 1 (last layer): out = emb16[r] + cur1[r] + in16[r] + acc (fp32 nt store).
// Streaming operands (edges, epilogue emb16/cur1, outputs) use non-temporal
// hints so they don't evict gather-resident lines from the 4MB/XCD L2s.
template <int MODE>
__global__ __launch_bounds__(256) void spmm_kernel(
    const int* __restrict__ row_ptr, const int2* __restrict__ edges,
    const __half* __restrict__ in16, const __half* __restrict__ emb16,
    const __half* __restrict__ cur1,
    float* __restrict__ out, __half* __restrict__ cur_out)
{
    int t = blockIdx.x * blockDim.x + threadIdx.x;
    int r = t >> 3;
    int l = t & 7;
    if (r >= N_NODES) return;
    int start = row_ptr[r];
    int end   = row_ptr[r + 1];
    int idx   = r * EMB + 8 * l;

    // prefetch epilogue terms (latency hides under the gather loop)
    union U4 { i4 v; __half2 h[4]; };
    U4 pe, p1, p2;
    if (MODE == 1) {
        pe.v = __builtin_nontemporal_load((const i4*)(emb16 + idx));
        p1.v = __builtin_nontemporal_load((const i4*)(cur1 + idx));
        p2.v = *(const i4*)(in16 + idx);   // in16 is also the gather table here
    }

    float a0 = 0.f, a1 = 0.f, a2 = 0.f, a3 = 0.f;
    float a4 = 0.f, a5 = 0.f, a6 = 0.f, a7 = 0.f;
    for (int j = start; j < end; j += 8) {
        i2 e[8];
#pragma unroll
        for (int k = 0; k < 8; ++k)
            e[k] = __builtin_nontemporal_load((const i2*)(edges + j + k)); // pad-read past end ok
#pragma unroll
        for (int k = 0; k < 8; ++k) {
            bool ok = (j + k < end);
            int   c = ok ? e[k].x : 0;
            float v = ok ? __int_as_float(e[k].y) : 0.0f;
            U4 g;
            g.v = *(const i4*)(in16 + c * EMB + 8 * l);   // 8 lanes x 16B = one 128B row
            float2 x0 = __half22float2(g.h[0]);
            float2 x1 = __half22float2(g.h[1]);
            float2 x2 = __half22float2(g.h[2]);
            float2 x3 = __half22float2(g.h[3]);
            a0 += v * x0.x; a1 += v * x0.y;
            a2 += v * x1.x; a3 += v * x1.y;
            a4 += v * x2.x; a5 += v * x2.y;
            a6 += v * x3.x; a7 += v * x3.y;
        }
    }

    if (MODE == 0) {
        U4 o;
        o.h[0] = __float22half2_rn(make_float2(a0, a1));
        o.h[1] = __float22half2_rn(make_float2(a2, a3));
        o.h[2] = __float22half2_rn(make_float2(a4, a5));
        o.h[3] = __float22half2_rn(make_float2(a6, a7));
        __builtin_nontemporal_store(o.v, (i4*)(cur_out + idx));
    } else {
        float2 e0 = __half22float2(pe.h[0]), e1 = __half22float2(pe.h[1]);
        float2 e2 = __half22float2(pe.h[2]), e3 = __half22float2(pe.h[3]);
        float2 c0 = __half22float2(p1.h[0]), c1 = __half22float2(p1.h[1]);
        float2 c2 = __half22float2(p1.h[2]), c3 = __half22float2(p1.h[3]);
        float2 d0 = __half22float2(p2.h[0]), d1 = __half22float2(p2.h[1]);
        float2 d2 = __half22float2(p2.h[2]), d3 = __half22float2(p2.h[3]);
        f4 o0 = { e0.x + c0.x + d0.x + a0, e0.y + c0.y + d0.y + a1,
                  e1.x + c1.x + d1.x + a2, e1.y + c1.y + d1.y + a3 };
        f4 o1 = { e2.x + c2.x + d2.x + a4, e2.y + c2.y + d2.y + a5,
                  e3.x + c3.x + d3.x + a6, e3.y + c3.y + d3.y + a7 };
        __builtin_nontemporal_store(o0, (f4*)(out + idx));
        __builtin_nontemporal_store(o1, (f4*)(out + idx + 4));
    }
}

extern "C" void kernel_launch(void* const* d_in, const int* in_sizes, int n_in,
                              void* d_out, int out_size, void* d_ws, size_t ws_size,
                              hipStream_t stream) {
    const float* user = (const float*)d_in[0];
    const float* item = (const float*)d_in[1];
    const int*   rows = (const int*)d_in[2];
    const int*   cols = (const int*)d_in[3];
    const float* vals = (const float*)d_in[4];
    float*       out  = (float*)d_out;

    // workspace layout (256B aligned), ~123 MB total
    char* p = (char*)d_ws;
    __half* emb16    = (__half*)p;  p += (size_t)N_ELEM * 2;            // 32 MB
    __half* cur1     = (__half*)p;  p += (size_t)N_ELEM * 2;            // 32 MB
    __half* cur2     = (__half*)p;  p += (size_t)N_ELEM * 2;            // 32 MB
    int2*   tmp      = (int2*)p;    p += (size_t)NBUCK * CAP * 8;       // 16.1 MB
    int2*   edges    = (int2*)p;    p += (size_t)N_EDGES * 8 + 256;     // 9.6 MB + pad
    int*    row_ptr  = (int*)p;     p += 1000448;                       // 250001*4 padded
    int*    bucket_base = (int*)p;  p += 1024;
    int*    bucket_cnt  = (int*)p;  p += 1024;                          // memset
    int*    chunkcur    = (int*)p;  p += 1024;                          // memset

    hipMemsetAsync(bucket_cnt, 0, 2048, stream);   // bucket_cnt + chunkcur

    bin_kernel<<<NBLK1, 256, 0, stream>>>(rows, cols, vals, chunkcur, bucket_cnt, tmp);
    scan245_kernel<<<1, 256, 0, stream>>>(bucket_cnt, bucket_base, row_ptr);
    place_init_kernel<<<NBUCK + INIT_BLOCKS, 256, 0, stream>>>(
        chunkcur, bucket_base, tmp, row_ptr, edges, user, item, emb16);

    const int spmm_blocks = (N_NODES * 8 + 255) / 256;   // 7813
    spmm_kernel<0><<<spmm_blocks, 256, 0, stream>>>(row_ptr, edges, emb16, emb16, cur1, out, cur1);
    spmm_kernel<0><<<spmm_blocks, 256, 0, stream>>>(row_ptr, edges, cur1, emb16, cur1, out, cur2);
    spmm_kernel<1><<<spmm_blocks, 256, 0, stream>>>(row_ptr, edges, cur2, emb16, cur1, out, nullptr);
}

// Round 2
// 279.757 us; speedup vs baseline: 1.0227x; 1.0227x over previous
//
#include <hip/hip_runtime.h>
#include <hip/hip_fp16.h>

#define USER_NUM 100000
#define ITEM_NUM 150000
#define N_NODES  250000
#define EMB      64
#define N_EDGES  1200000
#define N_ELEM   (N_NODES * EMB)   // 16,000,000

#define NBLK1 512                  // binning blocks
#define NBUCK 245                  // ceil(N_NODES/1024) buckets of 1024 rows
#define CAP   8192                 // records per bucket region in tmp
#define TB1   4096                 // phase-1 tile buffer (max padded 2344+245*7=4059)
#define INIT_BLOCKS 3907           // ceil(N_ELEM/16 / 256)

typedef float f4 __attribute__((ext_vector_type(4)));
typedef int   i4 __attribute__((ext_vector_type(4)));

// ------- fused phase 1: blocks [0,NBLK1) bin edges; rest do fp16 table init -------
// bin flush: sbuck[] byte array replaces the per-record 8-step LDS binary search.
__global__ __launch_bounds__(256) void bin_init_kernel(
    const int* __restrict__ rows, const int* __restrict__ cols,
    const float* __restrict__ vals,
    int* __restrict__ chunkcur, int* __restrict__ bucket_cnt,
    int2* __restrict__ tmp,
    const float* __restrict__ user, const float* __restrict__ item,
    __half* __restrict__ emb16)
{
    __shared__ int  scnt[256];            // per-bucket count, later placement cursor
    __shared__ int  spref[256];           // padded exclusive prefix (246 used)
    __shared__ int  schunk[NBUCK];        // global chunk base per bucket
    __shared__ unsigned char sbuck[TB1];  // slot -> bucket id (kills binary search)
    __shared__ int2 tilebuf[TB1];

    int t = threadIdx.x;

    if (blockIdx.x >= NBLK1) {
        // ---- init path: 16 elems/thread, fp32 user||item -> fp16 table ----
        int gi = (blockIdx.x - NBLK1) * 256 + t;
        if (gi < N_ELEM / 16) {
            int base = gi * 16;
            const int UE = USER_NUM * EMB;   // 6.4M, 16-aligned
            const f4* src = (base < UE) ? (const f4*)(user + base)
                                        : (const f4*)(item + (base - UE));
            f4 f0 = __builtin_nontemporal_load(src);
            f4 f1 = __builtin_nontemporal_load(src + 1);
            f4 f2 = __builtin_nontemporal_load(src + 2);
            f4 f3 = __builtin_nontemporal_load(src + 3);
            union { i4 v; __half2 h[4]; } a, b;
            a.h[0] = __float22half2_rn(make_float2(f0.x, f0.y));
            a.h[1] = __float22half2_rn(make_float2(f0.z, f0.w));
            a.h[2] = __float22half2_rn(make_float2(f1.x, f1.y));
            a.h[3] = __float22half2_rn(make_float2(f1.z, f1.w));
            b.h[0] = __float22half2_rn(make_float2(f2.x, f2.y));
            b.h[1] = __float22half2_rn(make_float2(f2.z, f2.w));
            b.h[2] = __float22half2_rn(make_float2(f3.x, f3.y));
            b.h[3] = __float22half2_rn(make_float2(f3.z, f3.w));
            ((i4*)(emb16 + base))[0] = a.v;
            ((i4*)(emb16 + base))[1] = b.v;
        }
        return;
    }

    // ---- bin path ----
    int b = blockIdx.x;
    int e0 = (int)((long long)b * N_EDGES / NBLK1);
    int e1 = (int)((long long)(b + 1) * N_EDGES / NBLK1);

    scnt[t] = 0;
    __syncthreads();
    for (int e = e0 + t; e < e1; e += 256)
        atomicAdd(&scnt[rows[e] >> 10], 1);
    __syncthreads();
    int realc = (t < NBUCK) ? scnt[t] : 0;
    int v     = (realc + 7) & ~7;            // pad to 8-record chunks
    __syncthreads();
    spref[t] = v;
    __syncthreads();
    for (int off = 1; off < 256; off <<= 1) {
        int u = (t >= off) ? spref[t - off] : 0;
        __syncthreads();
        spref[t] += u;
        __syncthreads();
    }
    int excl = spref[t] - v;
    __syncthreads();
    spref[t] = excl;                          // exclusive; spref[245]=total
    __syncthreads();
    int padded_total = spref[NBUCK];

    scnt[t] = excl;                           // placement cursor
    if (t < NBUCK) {
        schunk[t] = (v > 0) ? atomicAdd(&chunkcur[t], v >> 3) : 0;
        if (realc > 0) atomicAdd(&bucket_cnt[t], realc);
        // only pad slots need the -1 marker; real slots get overwritten below
        for (int k = realc; k < v; ++k) tilebuf[excl + k] = make_int2(-1, 0);
        // slot -> bucket map for the flush (replaces binary search)
        for (int k = 0; k < v; ++k) sbuck[excl + k] = (unsigned char)t;
    }
    __syncthreads();
    for (int e = e0 + t; e < e1; e += 256) {
        int r  = rows[e];
        int lp = atomicAdd(&scnt[r >> 10], 1);
        tilebuf[lp] = make_int2(((r & 1023) << 18) | cols[e], __float_as_int(vals[e]));
    }
    __syncthreads();
    // flush: every bucket group a whole number of 64B-aligned chunks
    for (int j = t; j < padded_total; j += 256) {
        int lo = sbuck[j];
        tmp[(size_t)lo * CAP + schunk[lo] * 8 + (j - spref[lo])] = tilebuf[j];
    }
}

// ------- phase 2: 245 blocks place CSR (scan of bucket counts fused in) -------
__global__ __launch_bounds__(256) void place_kernel(
    const int* __restrict__ chunkcur, const int* __restrict__ bucket_cnt,
    const int2* __restrict__ tmp,
    int* __restrict__ row_ptr, int2* __restrict__ edges)
{
    __shared__ int  shist[1024];
    __shared__ int  swave[256];
    __shared__ int  sbase[2];
    __shared__ int2 sstage[CAP];   // 64KB

    int t = threadIdx.x;
    int b = blockIdx.x;

    // fused scan of the 245 bucket counts -> this bucket's [base, base+cnt)
    int vv = (t < NBUCK) ? bucket_cnt[t] : 0;
    swave[t] = vv;
    __syncthreads();
    for (int off = 1; off < 256; off <<= 1) {
        int u = (t >= off) ? swave[t - off] : 0;
        __syncthreads();
        swave[t] += u;
        __syncthreads();
    }
    if (t == 0) {
        sbase[0] = (b == 0) ? 0 : swave[b - 1];
        sbase[1] = swave[b];
        if (b == 0) row_ptr[N_NODES] = N_EDGES;
    }
    __syncthreads();
    int bb  = sbase[0];
    int cnt = sbase[1] - sbase[0];

    int nrec = chunkcur[b] * 8;
    const int2* src = tmp + (size_t)b * CAP;

    for (int i = t; i < 1024; i += 256) shist[i] = 0;
    __syncthreads();
    for (int j = t; j < nrec; j += 256) {
        int x = src[j].x;
        if (x != -1) atomicAdd(&shist[x >> 18], 1);
    }
    __syncthreads();
    int h0 = shist[4 * t], h1 = shist[4 * t + 1], h2 = shist[4 * t + 2], h3 = shist[4 * t + 3];
    int sum = h0 + h1 + h2 + h3;
    swave[t] = sum;
    __syncthreads();
    for (int off = 1; off < 256; off <<= 1) {
        int u = (t >= off) ? swave[t - off] : 0;
        __syncthreads();
        swave[t] += u;
        __syncthreads();
    }
    int base = swave[t] - sum;
    __syncthreads();
    shist[4 * t]     = base;
    shist[4 * t + 1] = base + h0;
    shist[4 * t + 2] = base + h0 + h1;
    shist[4 * t + 3] = base + h0 + h1 + h2;
    __syncthreads();
    for (int i = t; i < 1024; i += 256) {
        int idx = b * 1024 + i;
        if (idx < N_NODES) row_ptr[idx] = bb + shist[i];
    }
    __syncthreads();
    for (int j = t; j < nrec; j += 256) {
        int2 rec = src[j];
        if (rec.x != -1) {
            int lp = atomicAdd(&shist[rec.x >> 18], 1);
            sstage[lp] = make_int2(rec.x & 0x3FFFF, rec.y);
        }
    }
    __syncthreads();
    for (int j = t; j < cnt; j += 256)
        edges[bb + j] = sstage[j];
}

// ---------------- fused SpMM: quarter-wave (16 lanes) per row, ILP-8 ----------------
// Lane l owns dims [4l, 4l+4). MODE 0: cur_out = acc (fp16).
// MODE 1 (last layer): out = emb16[r] + cur1[r] + in16[r] + acc (fp32 store).
template <int MODE>
__global__ __launch_bounds__(256) void spmm_kernel(
    const int* __restrict__ row_ptr, const int2* __restrict__ edges,
    const __half* __restrict__ in16, const __half* __restrict__ emb16,
    const __half* __restrict__ cur1,
    float* __restrict__ out, __half* __restrict__ cur_out)
{
    int t = blockIdx.x * blockDim.x + threadIdx.x;
    int r = t >> 4;
    int l = t & 15;
    if (r >= N_NODES) return;
    int start = row_ptr[r];
    int end   = row_ptr[r + 1];
    int idx   = r * EMB + 4 * l;

    // prefetch epilogue terms (latency hides under the gather loop)
    union { int2 i; __half2 h[2]; } pe, p1, p2;
    if (MODE == 1) {
        pe.i = *(const int2*)(emb16 + idx);
        p1.i = *(const int2*)(cur1 + idx);
        p2.i = *(const int2*)(in16 + idx);
    }

    float ax = 0.f, ay = 0.f, az = 0.f, aw = 0.f;
    for (int j = start; j < end; j += 8) {
        int2 e[8];
#pragma unroll
        for (int k = 0; k < 8; ++k) e[k] = edges[j + k];   // pad-read past end ok
#pragma unroll
        for (int k = 0; k < 8; ++k) {
            bool ok = (j + k < end);
            int   c = ok ? e[k].x : 0;
            float v = ok ? __int_as_float(e[k].y) : 0.0f;
            union { int2 i; __half2 h[2]; } g;
            g.i = *(const int2*)(in16 + c * EMB + 4 * l);
            float2 x0 = __half22float2(g.h[0]);
            float2 x1 = __half22float2(g.h[1]);
            ax += v * x0.x; ay += v * x0.y;
            az += v * x1.x; aw += v * x1.y;
        }
    }

    if (MODE == 0) {
        union { int2 i; __half2 h[2]; } o;
        o.h[0] = __float22half2_rn(make_float2(ax, ay));
        o.h[1] = __float22half2_rn(make_float2(az, aw));
        *(int2*)(cur_out + idx) = o.i;
    } else {
        float2 e0 = __half22float2(pe.h[0]), e1 = __half22float2(pe.h[1]);
        float2 c0 = __half22float2(p1.h[0]), c1 = __half22float2(p1.h[1]);
        float2 d0 = __half22float2(p2.h[0]), d1 = __half22float2(p2.h[1]);
        float4 o = make_float4(e0.x + c0.x + d0.x + ax,
                               e0.y + c0.y + d0.y + ay,
                               e1.x + c1.x + d1.x + az,
                               e1.y + c1.y + d1.y + aw);
        *(float4*)(out + idx) = o;
    }
}

extern "C" void kernel_launch(void* const* d_in, const int* in_sizes, int n_in,
                              void* d_out, int out_size, void* d_ws, size_t ws_size,
                              hipStream_t stream) {
    const float* user = (const float*)d_in[0];
    const float* item = (const float*)d_in[1];
    const int*   rows = (const int*)d_in[2];
    const int*   cols = (const int*)d_in[3];
    const float* vals = (const float*)d_in[4];
    float*       out  = (float*)d_out;

    // workspace layout (256B aligned), ~123 MB total
    char* p = (char*)d_ws;
    __half* emb16    = (__half*)p;  p += (size_t)N_ELEM * 2;            // 32 MB
    __half* cur1     = (__half*)p;  p += (size_t)N_ELEM * 2;            // 32 MB
    __half* cur2     = (__half*)p;  p += (size_t)N_ELEM * 2;            // 32 MB
    int2*   tmp      = (int2*)p;    p += (size_t)NBUCK * CAP * 8;       // 16.1 MB
    int2*   edges    = (int2*)p;    p += (size_t)N_EDGES * 8 + 256;     // 9.6 MB + pad
    int*    row_ptr  = (int*)p;     p += 1000448;                       // 250001*4 padded
    int*    bucket_base = (int*)p;  p += 1024;                          // (unused now)
    int*    bucket_cnt  = (int*)p;  p += 1024;                          // memset
    int*    chunkcur    = (int*)p;  p += 1024;                          // memset

    hipMemsetAsync(bucket_cnt, 0, 2048, stream);   // bucket_cnt + chunkcur

    bin_init_kernel<<<NBLK1 + INIT_BLOCKS, 256, 0, stream>>>(
        rows, cols, vals, chunkcur, bucket_cnt, tmp, user, item, emb16);
    place_kernel<<<NBUCK, 256, 0, stream>>>(chunkcur, bucket_cnt, tmp, row_ptr, edges);

    const int spmm_blocks = (N_NODES * 16 + 255) / 256;   // 15625
    spmm_kernel<0><<<spmm_blocks, 256, 0, stream>>>(row_ptr, edges, emb16, emb16, cur1, out, cur1);
    spmm_kernel<0><<<spmm_blocks, 256, 0, stream>>>(row_ptr, edges, cur1, emb16, cur1, out, cur2);
    spmm_kernel<1><<<spmm_blocks, 256, 0, stream>>>(row_ptr, edges, cur2, emb16, cur1, out, nullptr);
}